// Round 3
// baseline (560.018 us; speedup 1.0000x reference)
//
#include <hip/hip_runtime.h>
#include <hip/hip_bf16.h>
#include <math.h>

typedef __hip_bfloat16 bf16;
typedef __attribute__((ext_vector_type(8))) short short8;
typedef __attribute__((ext_vector_type(4))) float floatx4;

#define EMB   1024
#define SEQ   2048
#define BATCH 4
#define M_TOK 8192
#define HEADS 16
#define HDIM  64
#define FFDIM 4096
#define KVB   64

typedef __attribute__((address_space(3))) void lds_t;
typedef __attribute__((address_space(1))) void glob_t;

static __device__ __forceinline__ void gll16(const bf16* g, bf16* l) {
  __builtin_amdgcn_global_load_lds((const glob_t*)g, (lds_t*)l, 16, 0, 0);
}

template<int N>
static __device__ __forceinline__ void wait_vmcnt() {
  if constexpr (N == 0) asm volatile("s_waitcnt vmcnt(0)" ::: "memory");
  else if constexpr (N == 6) asm volatile("s_waitcnt vmcnt(6)" ::: "memory");
  else if constexpr (N == 8) asm volatile("s_waitcnt vmcnt(8)" ::: "memory");
}

static __device__ __forceinline__ unsigned short f2bu(float f) {
  union { __hip_bfloat16 h; unsigned short u; } cv;
  cv.h = __float2bfloat16(f);
  return cv.u;
}

static __device__ __forceinline__ float gelu_f(float x) {
  float t = tanhf(0.7978845608028654f * (x + 0.044715f * x * x * x));
  return 0.5f * x * (1.0f + t);
}

// ---- weight convert + transpose: W fp32 [Kd][Nd] -> Wt bf16 [Nd][Kd] ----
__global__ __launch_bounds__(256) void wconv_kernel(const float* __restrict__ W,
                                                    bf16* __restrict__ Wt,
                                                    int Kd, int Nd) {
  __shared__ float tile[32][33];
  int n0 = blockIdx.x * 32, k0 = blockIdx.y * 32;
  int tx = threadIdx.x & 31, ty = threadIdx.x >> 5;
  #pragma unroll
  for (int j = 0; j < 32; j += 8)
    tile[ty + j][tx] = W[(size_t)(k0 + ty + j) * Nd + n0 + tx];
  __syncthreads();
  #pragma unroll
  for (int j = 0; j < 32; j += 8)
    Wt[(size_t)(n0 + ty + j) * Kd + k0 + tx] = __float2bfloat16(tile[tx][ty + j]);
}

// ---- LayerNorm (ddof=1): fp32 [8192][1024] -> bf16 ----
__global__ __launch_bounds__(256) void ln_kernel(const float* __restrict__ x,
                                                 const float* __restrict__ sc,
                                                 const float* __restrict__ bi,
                                                 bf16* __restrict__ out) {
  int row = blockIdx.x, tid = threadIdx.x;
  const float4* xr = (const float4*)(x + (size_t)row * EMB);
  float4 v = xr[tid];
  float s  = v.x + v.y + v.z + v.w;
  float s2 = v.x * v.x + v.y * v.y + v.z * v.z + v.w * v.w;
  #pragma unroll
  for (int off = 1; off < 64; off <<= 1) {
    s  += __shfl_xor(s, off);
    s2 += __shfl_xor(s2, off);
  }
  __shared__ float red[8];
  int wv = tid >> 6;
  if ((tid & 63) == 0) { red[wv] = s; red[4 + wv] = s2; }
  __syncthreads();
  s  = red[0] + red[1] + red[2] + red[3];
  s2 = red[4] + red[5] + red[6] + red[7];
  float mean = s * (1.0f / EMB);
  float var  = (s2 - (float)EMB * mean * mean) * (1.0f / (EMB - 1));
  float rstd = rsqrtf(var + 1e-5f);
  float4 scv = ((const float4*)sc)[tid];
  float4 biv = ((const float4*)bi)[tid];
  ushort4 o;
  o.x = f2bu((v.x - mean) * rstd * scv.x + biv.x);
  o.y = f2bu((v.y - mean) * rstd * scv.y + biv.y);
  o.z = f2bu((v.z - mean) * rstd * scv.z + biv.z);
  o.w = f2bu((v.w - mean) * rstd * scv.w + biv.w);
  ((ushort4*)(out + (size_t)row * EMB))[tid] = o;
}

// ---- 8-phase 256-tile GEMM (T2+T3+T4+T5): C[M][Nd] = A[M][Kd] * Bt[Nd][Kd]^T
// 512 thr = 8 waves (WMv x WNv). BK=64, 4 phases/K-tile (kk x m-half), counted
// vmcnt at K-tile boundary only. LDS XOR-swizzle slot^=(row&7) applied on the
// global SOURCE of global_load_lds (linear dest) + on ds_read (rule 21).
// MODE 3: fp32 out = C+bias+resid   MODE 4: bf16 out = gelu(C+bias)
// MODE 6: fused QKV scatter (z: 0=q scaled, 1=k, 2=vT)
template<int BN, int WMv, int WNv, int Kd, int MODE>
__global__ __launch_bounds__(512, 1) void gemm8_kernel(
    const bf16* __restrict__ A, const bf16* __restrict__ Bt,
    const float* __restrict__ bias, const float* __restrict__ resid,
    void* __restrict__ outp) {
  constexpr int BM = 256, BK = 64;
  constexpr int MR = BM / WMv / 16;            // frags per wave in M (8 or 4)
  constexpr int NR = BN / WNv / 16;            // frags per wave in N (4)
  constexpr int HR = MR / 2;
  constexpr int ACH = (BM * BK) / 8 / 512;     // A 16B-chunks per thread (4)
  constexpr int BCH = (BN * BK) / 8 / 512;     // B chunks per thread (4 or 2)
  constexpr int NLD = ACH + BCH;               // stage loads/thread (8 or 6)
  constexpr int NT = Kd / BK;

  __shared__ __align__(16) bf16 As[2][BM * BK];
  __shared__ __align__(16) bf16 Bs[2][BN * BK];

  const int tid = threadIdx.x;
  const int lane = tid & 63, wave = tid >> 6;
  const int lo = lane & 15, hi = lane >> 4, lo7 = lane & 7;
  const int wm = wave / WNv, wn = wave % WNv;
  const int m0 = blockIdx.x * BM, n0 = blockIdx.y * BN;

  const bf16* Bt2 = Bt;
  if constexpr (MODE == 6) Bt2 = Bt + ((size_t)blockIdx.z << 20);
  const bf16* Ag = A + (size_t)m0 * Kd;
  const bf16* Bg = Bt2 + (size_t)n0 * Kd;

  auto STAGE = [&](int kt, int bufb) {
    const int k0 = kt * BK;
    #pragma unroll
    for (int i = 0; i < ACH; i++) {
      const int ch = i * 512 + tid;
      const int r = ch >> 3, s = (ch & 7) ^ (r & 7);
      gll16(Ag + (size_t)r * Kd + k0 + s * 8, (bf16*)As[bufb] + ch * 8);
    }
    #pragma unroll
    for (int i = 0; i < BCH; i++) {
      const int ch = i * 512 + tid;
      const int r = ch >> 3, s = (ch & 7) ^ (r & 7);
      gll16(Bg + (size_t)r * Kd + k0 + s * 8, (bf16*)Bs[bufb] + ch * 8);
    }
  };

  floatx4 acc[MR][NR];
  #pragma unroll
  for (int i = 0; i < MR; i++)
    #pragma unroll
    for (int j = 0; j < NR; j++)
      #pragma unroll
      for (int r = 0; r < 4; r++) acc[i][j][r] = 0.0f;

  STAGE(0, 0);

  for (int t = 0; t < NT; ++t) {
    const int bb = t & 1;
    const bf16* Ab = As[bb];
    const bf16* Bb = Bs[bb];
    short8 bfr[NR];
    #pragma unroll
    for (int p = 0; p < 4; p++) {
      const int kk = p >> 1, mh = p & 1;
      if (p == 0) {
        if (t + 1 < NT) { STAGE(t + 1, bb ^ 1); wait_vmcnt<NLD>(); }
        else            { wait_vmcnt<0>(); }
        __builtin_amdgcn_s_barrier();       // new buffer visible to all waves
        __builtin_amdgcn_sched_barrier(0);
      }
      short8 af[HR];
      #pragma unroll
      for (int i = 0; i < HR; i++) {
        const int r = wm * (MR * 16) + (mh * HR + i) * 16 + lo;
        af[i] = *(const short8*)&Ab[r * 64 + ((kk * 4 + hi) ^ lo7) * 8];
      }
      if (mh == 0) {
        #pragma unroll
        for (int n = 0; n < NR; n++) {
          const int r = wn * (NR * 16) + n * 16 + lo;
          bfr[n] = *(const short8*)&Bb[r * 64 + ((kk * 4 + hi) ^ lo7) * 8];
        }
      }
      if (p > 0) __builtin_amdgcn_s_barrier();   // phase alignment
      asm volatile("s_waitcnt lgkmcnt(0)" ::: "memory");
      __builtin_amdgcn_sched_barrier(0);         // rule 18
      __builtin_amdgcn_s_setprio(1);
      #pragma unroll
      for (int i = 0; i < HR; i++)
        #pragma unroll
        for (int n = 0; n < NR; n++)
          acc[mh * HR + i][n] =
              __builtin_amdgcn_mfma_f32_16x16x32_bf16(af[i], bfr[n], acc[mh * HR + i][n], 0, 0, 0);
      __builtin_amdgcn_s_setprio(0);
      __builtin_amdgcn_s_barrier();
    }
  }

  const int mwb = m0 + wm * (MR * 16);
  const int nwb = n0 + wn * (NR * 16);
  #pragma unroll
  for (int i = 0; i < MR; i++) {
    #pragma unroll
    for (int j = 0; j < NR; j++) {
      const int mb = mwb + i * 16 + hi * 4;     // 4 consecutive m = mb+r
      const int n  = nwb + j * 16 + lo;
      if constexpr (MODE == 6) {
        const int z = blockIdx.z;
        const int bx = mb >> 11, hhh = n >> 6, d = n & 63;
        bf16* ob = (bf16*)outp + ((size_t)z << 23);
        if (z == 2) {
          ushort4 pk;
          pk.x = f2bu(acc[i][j][0]); pk.y = f2bu(acc[i][j][1]);
          pk.z = f2bu(acc[i][j][2]); pk.w = f2bu(acc[i][j][3]);
          *(ushort4*)&ob[((size_t)(bx * HEADS + hhh) * HDIM + d) * SEQ + (mb & 2047)] = pk;
        } else {
          const float sc = (z == 0) ? 0.125f : 1.0f;
          #pragma unroll
          for (int r = 0; r < 4; r++) {
            const int ss = (mb + r) & 2047;
            ob[((size_t)(bx * HEADS + hhh) * SEQ + ss) * HDIM + d] =
                __float2bfloat16(acc[i][j][r] * sc);
          }
        }
      } else if constexpr (MODE == 3) {
        #pragma unroll
        for (int r = 0; r < 4; r++) {
          const int m = mb + r;
          ((float*)outp)[(size_t)m * EMB + n] =
              acc[i][j][r] + bias[n] + resid[(size_t)m * EMB + n];
        }
      } else if constexpr (MODE == 4) {
        #pragma unroll
        for (int r = 0; r < 4; r++)
          ((bf16*)outp)[(size_t)(mb + r) * FFDIM + n] =
              __float2bfloat16(gelu_f(acc[i][j][r] + bias[n]));
      }
    }
  }
}

// ---- causal flash attention, staged + double-buffered (round-2 + T5) ----
__global__ __launch_bounds__(256, 2) void attn_kernel(
    const bf16* __restrict__ q, const bf16* __restrict__ k,
    const bf16* __restrict__ vt, bf16* __restrict__ ctx) {
  __shared__ __align__(16) char KVs[2][2][64 * 128];  // [buf][K|V][row 64][128B]
  __shared__ __align__(16) char Pls[4][4096];         // per-wave P [32][64] bf16, swz
  const int bh = blockIdx.x, qt = blockIdx.y;
  const int tid = threadIdx.x;
  const int wave = tid >> 6, lane = tid & 63;
  const int lo = lane & 15, hi = lane >> 4;
  const int lo7 = lo & 7;
  const int q0 = qt * 128;
  const int q0w = q0 + wave * 32;
  const int qmax = q0w + 31;

  const bf16* qp = q  + ((size_t)bh * SEQ + q0w) * HDIM;
  const bf16* kp = k  + (size_t)bh * SEQ * HDIM;
  const bf16* vp = vt + (size_t)bh * HDIM * SEQ;

  short8 qf[2][2];
  #pragma unroll
  for (int m = 0; m < 2; m++)
    #pragma unroll
    for (int kk = 0; kk < 2; kk++)
      qf[m][kk] = *(const short8*)&qp[(size_t)(m * 16 + lo) * HDIM + kk * 32 + hi * 8];

  float m_run[2] = {-1e30f, -1e30f};
  float l_run[2] = {0.0f, 0.0f};
  floatx4 o[4][2];
  #pragma unroll
  for (int df = 0; df < 4; df++)
    #pragma unroll
    for (int m = 0; m < 2; m++)
      #pragma unroll
      for (int r = 0; r < 4; r++) o[df][m][r] = 0.0f;

  const int nt = 2 * qt + 2;

  const int c0 = tid, c1 = tid + 256;
  const int r0 = c0 >> 3, s0 = (c0 & 7) ^ (r0 & 7);
  const int r1 = c1 >> 3, s1 = (c1 & 7) ^ (r1 & 7);

  gll16(kp + (size_t)r0 * HDIM + s0 * 8, (bf16*)&KVs[0][0][c0 * 16]);
  gll16(vp + (size_t)r0 * SEQ + s0 * 8,  (bf16*)&KVs[0][1][c0 * 16]);
  gll16(kp + (size_t)r1 * HDIM + s1 * 8, (bf16*)&KVs[0][0][c1 * 16]);
  gll16(vp + (size_t)r1 * SEQ + s1 * 8,  (bf16*)&KVs[0][1][c1 * 16]);

  for (int t = 0; t < nt; ++t) {
    const int buf = t & 1;
    const int k0 = t * KVB;
    if (t + 1 < nt) {
      const int kn = k0 + KVB;
      gll16(kp + (size_t)(kn + r0) * HDIM + s0 * 8, (bf16*)&KVs[buf ^ 1][0][c0 * 16]);
      gll16(vp + (size_t)r0 * SEQ + kn + s0 * 8,    (bf16*)&KVs[buf ^ 1][1][c0 * 16]);
      gll16(kp + (size_t)(kn + r1) * HDIM + s1 * 8, (bf16*)&KVs[buf ^ 1][0][c1 * 16]);
      gll16(vp + (size_t)r1 * SEQ + kn + s1 * 8,    (bf16*)&KVs[buf ^ 1][1][c1 * 16]);
      asm volatile("s_waitcnt vmcnt(4)" ::: "memory");
    } else {
      asm volatile("s_waitcnt vmcnt(0)" ::: "memory");
    }
    __builtin_amdgcn_s_barrier();
    __builtin_amdgcn_sched_barrier(0);

    if (k0 <= qmax) {
      const char* Kb = KVs[buf][0];
      const char* Vb = KVs[buf][1];
      floatx4 sfr[4][2];
      __builtin_amdgcn_s_setprio(1);
      #pragma unroll
      for (int kf = 0; kf < 4; kf++) {
        const int rowb = (kf * 16 + lo) * 128;
        short8 kf0 = *(const short8*)(Kb + rowb + (( 0 + hi * 16) ^ (lo7 << 4)));
        short8 kf1 = *(const short8*)(Kb + rowb + ((64 + hi * 16) ^ (lo7 << 4)));
        #pragma unroll
        for (int m = 0; m < 2; m++) {
          floatx4 z = {0.0f, 0.0f, 0.0f, 0.0f};
          z = __builtin_amdgcn_mfma_f32_16x16x32_bf16(kf0, qf[m][0], z, 0, 0, 0);
          z = __builtin_amdgcn_mfma_f32_16x16x32_bf16(kf1, qf[m][1], z, 0, 0, 0);
          sfr[kf][m] = z;
        }
      }
      __builtin_amdgcn_s_setprio(0);
      if (k0 + KVB - 1 > q0w) {
        #pragma unroll
        for (int m = 0; m < 2; m++) {
          const int qg = q0w + m * 16 + lo;
          #pragma unroll
          for (int kf = 0; kf < 4; kf++)
            #pragma unroll
            for (int r = 0; r < 4; r++) {
              const int key = k0 + kf * 16 + hi * 4 + r;
              if (key > qg) sfr[kf][m][r] = -1e30f;
            }
        }
      }
      float alpha[2];
      #pragma unroll
      for (int m = 0; m < 2; m++) {
        float tmax = -1e30f;
        #pragma unroll
        for (int kf = 0; kf < 4; kf++)
          #pragma unroll
          for (int r = 0; r < 4; r++) tmax = fmaxf(tmax, sfr[kf][m][r]);
        tmax = fmaxf(tmax, __shfl_xor(tmax, 16));
        tmax = fmaxf(tmax, __shfl_xor(tmax, 32));
        const float mn = fmaxf(m_run[m], tmax);
        alpha[m] = __expf(m_run[m] - mn);
        m_run[m] = mn;
        float ps = 0.0f;
        const int prow = (m * 16 + lo) * 128;
        #pragma unroll
        for (int kf = 0; kf < 4; kf++) {
          float p0 = __expf(sfr[kf][m][0] - mn);
          float p1 = __expf(sfr[kf][m][1] - mn);
          float p2 = __expf(sfr[kf][m][2] - mn);
          float p3 = __expf(sfr[kf][m][3] - mn);
          ps += (p0 + p1) + (p2 + p3);
          ushort4 pk;
          pk.x = f2bu(p0); pk.y = f2bu(p1); pk.z = f2bu(p2); pk.w = f2bu(p3);
          *(ushort4*)(Pls[wave] + prow + ((kf * 32 + hi * 8) ^ (lo7 << 4))) = pk;
        }
        ps += __shfl_xor(ps, 16);
        ps += __shfl_xor(ps, 32);
        l_run[m] = l_run[m] * alpha[m] + ps;
      }
      asm volatile("s_waitcnt lgkmcnt(0)" ::: "memory");
      __builtin_amdgcn_sched_barrier(0);
      short8 pa[2][2];
      #pragma unroll
      for (int m = 0; m < 2; m++)
        #pragma unroll
        for (int kk2 = 0; kk2 < 2; kk2++)
          pa[m][kk2] = *(const short8*)(Pls[wave] + (m * 16 + lo) * 128 +
                                        ((kk2 * 64 + hi * 16) ^ (lo7 << 4)));
      float ar[2][4];
      #pragma unroll
      for (int m = 0; m < 2; m++)
        #pragma unroll
        for (int r = 0; r < 4; r++) ar[m][r] = __shfl(alpha[m], hi * 4 + r);
      #pragma unroll
      for (int df = 0; df < 4; df++)
        #pragma unroll
        for (int m = 0; m < 2; m++)
          #pragma unroll
          for (int r = 0; r < 4; r++) o[df][m][r] *= ar[m][r];
      __builtin_amdgcn_s_setprio(1);
      #pragma unroll
      for (int df = 0; df < 4; df++) {
        const int rowb = (df * 16 + lo) * 128;
        short8 vf0 = *(const short8*)(Vb + rowb + (( 0 + hi * 16) ^ (lo7 << 4)));
        short8 vf1 = *(const short8*)(Vb + rowb + ((64 + hi * 16) ^ (lo7 << 4)));
        #pragma unroll
        for (int m = 0; m < 2; m++) {
          o[df][m] = __builtin_amdgcn_mfma_f32_16x16x32_bf16(pa[m][0], vf0, o[df][m], 0, 0, 0);
          o[df][m] = __builtin_amdgcn_mfma_f32_16x16x32_bf16(pa[m][1], vf1, o[df][m], 0, 0, 0);
        }
      }
      __builtin_amdgcn_s_setprio(0);
    }
    __builtin_amdgcn_s_barrier();
    __builtin_amdgcn_sched_barrier(0);
  }

  const int b = bh >> 4, hh = bh & 15;
  #pragma unroll
  for (int m = 0; m < 2; m++) {
    float lr[4];
    #pragma unroll
    for (int r = 0; r < 4; r++) lr[r] = __shfl(l_run[m], hi * 4 + r);
    #pragma unroll
    for (int df = 0; df < 4; df++)
      #pragma unroll
      for (int r = 0; r < 4; r++) {
        const int srow = q0w + m * 16 + hi * 4 + r;
        ctx[((size_t)(b * SEQ + srow)) * EMB + hh * HDIM + df * 16 + lo] =
            __float2bfloat16(o[df][m][r] / lr[r]);
      }
  }
}

extern "C" void kernel_launch(void* const* d_in, const int* in_sizes, int n_in,
                              void* d_out, int out_size, void* d_ws, size_t ws_size,
                              hipStream_t stream) {
  const float* x   = (const float*)d_in[0];
  const float* Wq  = (const float*)d_in[1];
  const float* Wk  = (const float*)d_in[2];
  const float* Wv  = (const float*)d_in[3];
  const float* Wo  = (const float*)d_in[4];
  const float* bo  = (const float*)d_in[5];
  const float* l1s = (const float*)d_in[6];
  const float* l1b = (const float*)d_in[7];
  const float* l2s = (const float*)d_in[8];
  const float* l2b = (const float*)d_in[9];
  const float* W1  = (const float*)d_in[10];
  const float* b1  = (const float*)d_in[11];
  const float* W2  = (const float*)d_in[12];
  const float* b2  = (const float*)d_in[13];
  float* out = (float*)d_out;

  char* ws = (char*)d_ws;
  bf16* hbuf   = (bf16*)(ws);
  bf16* qbuf   = (bf16*)(ws + ((size_t)16 << 20));
  bf16* kbuf   = (bf16*)(ws + ((size_t)32 << 20));
  bf16* vbuf   = (bf16*)(ws + ((size_t)48 << 20));
  bf16* ctxbuf = hbuf;
  bf16* gbuf   = (bf16*)(ws);
  bf16* h2buf  = (bf16*)(ws + ((size_t)64 << 20));
  bf16* WqT    = (bf16*)(ws + ((size_t)80 << 20));
  bf16* WkT    = WqT + (1u << 20);
  bf16* WvT    = WkT + (1u << 20);
  bf16* WoT    = WvT + (1u << 20);
  bf16* W1T    = WoT + (1u << 20);
  bf16* W2T    = W1T + (4u << 20);

  wconv_kernel<<<dim3(32, 32), 256, 0, stream>>>(Wq, WqT, 1024, 1024);
  wconv_kernel<<<dim3(32, 32), 256, 0, stream>>>(Wk, WkT, 1024, 1024);
  wconv_kernel<<<dim3(32, 32), 256, 0, stream>>>(Wv, WvT, 1024, 1024);
  wconv_kernel<<<dim3(32, 32), 256, 0, stream>>>(Wo, WoT, 1024, 1024);
  wconv_kernel<<<dim3(128, 32), 256, 0, stream>>>(W1, W1T, 1024, 4096);
  wconv_kernel<<<dim3(32, 128), 256, 0, stream>>>(W2, W2T, 4096, 1024);

  ln_kernel<<<8192, 256, 0, stream>>>(x, l1s, l1b, hbuf);

  // fused QKV (256x128 tile, 4Mx2N waves): z=0 q(scaled), z=1 k, z=2 vT
  gemm8_kernel<128, 4, 2, 1024, 6><<<dim3(32, 8, 3), 512, 0, stream>>>(
      hbuf, WqT, nullptr, nullptr, qbuf);

  attn_kernel<<<dim3(64, 16), 256, 0, stream>>>(qbuf, kbuf, vbuf, ctxbuf);

  // Wo + bias + residual (fp32 out)
  gemm8_kernel<128, 4, 2, 1024, 3><<<dim3(32, 8), 512, 0, stream>>>(
      ctxbuf, WoT, bo, x, (void*)out);
  ln_kernel<<<8192, 256, 0, stream>>>(out, l2s, l2b, h2buf);
  // FF1: 256x256 tile, gelu
  gemm8_kernel<256, 2, 4, 1024, 4><<<dim3(32, 16), 512, 0, stream>>>(
      h2buf, W1T, b1, nullptr, gbuf);
  // FF2: 256x128 tile, bias + residual (fp32 out)
  gemm8_kernel<128, 4, 2, 4096, 3><<<dim3(32, 8), 512, 0, stream>>>(
      gbuf, W2T, b2, out, (void*)out);
}

// Round 4
// 545.065 us; speedup vs baseline: 1.0274x; 1.0274x over previous
//
#include <hip/hip_runtime.h>
#include <hip/hip_bf16.h>
#include <math.h>

typedef __hip_bfloat16 bf16;
typedef __attribute__((ext_vector_type(8))) short short8;
typedef __attribute__((ext_vector_type(4))) float floatx4;

#define EMB   1024
#define SEQ   2048
#define BATCH 4
#define M_TOK 8192
#define HEADS 16
#define HDIM  64
#define FFDIM 4096
#define KVB   64

typedef __attribute__((address_space(3))) void lds_t;
typedef __attribute__((address_space(1))) void glob_t;

static __device__ __forceinline__ void gll16(const bf16* g, bf16* l) {
  __builtin_amdgcn_global_load_lds((const glob_t*)g, (lds_t*)l, 16, 0, 0);
}

static __device__ __forceinline__ unsigned short f2bu(float f) {
  union { __hip_bfloat16 h; unsigned short u; } cv;
  cv.h = __float2bfloat16(f);
  return cv.u;
}

static __device__ __forceinline__ float gelu_f(float x) {
  float t = tanhf(0.7978845608028654f * (x + 0.044715f * x * x * x));
  return 0.5f * x * (1.0f + t);
}

// ---- weight convert + transpose: W fp32 [Kd][Nd] -> Wt bf16 [Nd][Kd] ----
__global__ __launch_bounds__(256) void wconv_kernel(const float* __restrict__ W,
                                                    bf16* __restrict__ Wt,
                                                    int Kd, int Nd) {
  __shared__ float tile[32][33];
  int n0 = blockIdx.x * 32, k0 = blockIdx.y * 32;
  int tx = threadIdx.x & 31, ty = threadIdx.x >> 5;
  #pragma unroll
  for (int j = 0; j < 32; j += 8)
    tile[ty + j][tx] = W[(size_t)(k0 + ty + j) * Nd + n0 + tx];
  __syncthreads();
  #pragma unroll
  for (int j = 0; j < 32; j += 8)
    Wt[(size_t)(n0 + ty + j) * Kd + k0 + tx] = __float2bfloat16(tile[tx][ty + j]);
}

// ---- LayerNorm (ddof=1): fp32 [8192][1024] -> bf16 ----
__global__ __launch_bounds__(256) void ln_kernel(const float* __restrict__ x,
                                                 const float* __restrict__ sc,
                                                 const float* __restrict__ bi,
                                                 bf16* __restrict__ out) {
  int row = blockIdx.x, tid = threadIdx.x;
  const float4* xr = (const float4*)(x + (size_t)row * EMB);
  float4 v = xr[tid];
  float s  = v.x + v.y + v.z + v.w;
  float s2 = v.x * v.x + v.y * v.y + v.z * v.z + v.w * v.w;
  #pragma unroll
  for (int off = 1; off < 64; off <<= 1) {
    s  += __shfl_xor(s, off);
    s2 += __shfl_xor(s2, off);
  }
  __shared__ float red[8];
  int wv = tid >> 6;
  if ((tid & 63) == 0) { red[wv] = s; red[4 + wv] = s2; }
  __syncthreads();
  s  = red[0] + red[1] + red[2] + red[3];
  s2 = red[4] + red[5] + red[6] + red[7];
  float mean = s * (1.0f / EMB);
  float var  = (s2 - (float)EMB * mean * mean) * (1.0f / (EMB - 1));
  float rstd = rsqrtf(var + 1e-5f);
  float4 scv = ((const float4*)sc)[tid];
  float4 biv = ((const float4*)bi)[tid];
  ushort4 o;
  o.x = f2bu((v.x - mean) * rstd * scv.x + biv.x);
  o.y = f2bu((v.y - mean) * rstd * scv.y + biv.y);
  o.z = f2bu((v.z - mean) * rstd * scv.z + biv.z);
  o.w = f2bu((v.w - mean) * rstd * scv.w + biv.w);
  ((ushort4*)(out + (size_t)row * EMB))[tid] = o;
}

// ---- 256-tile 4-quadrant-phase GEMM (m201-style): C = A[M][Kd] * Bt[N][Kd]^T
// 512 thr = 8 waves (2M x 4N), BK=64. Per phase: {ds_reads of next quadrant's
// new half + stage 1 half-tile of t+1} barrier {16 (or 8) MFMA} barrier.
// One counted vmcnt(2) per K-tile (guarantees ALL of tile t landed; staging
// leads by a full tile). Halves are banded so they match quadrant consumption.
// MODE 3: fp32 out = C+bias+resid   MODE 4: bf16 out = gelu(C+bias)
// MODE 6: fused QKV scatter, n in [0,3072): z=n>>10 (0=q scaled,1=k,2=vT)
template<int BN, int Kd, int MODE>
__global__ __launch_bounds__(512, 1) void gemm8_kernel(
    const bf16* __restrict__ A, const bf16* __restrict__ Bt,
    const float* __restrict__ bias, const float* __restrict__ resid,
    void* __restrict__ outp) {
  constexpr int BM = 256, BK = 64;
  constexpr int MR = 8, MRh = 4;
  constexpr int NR = BN / 64, NRh = NR / 2;      // 4/2 or 2/1
  constexpr int BLOADS = BN / 128;               // gloads per B half (2 or 1)
  constexpr int NT = Kd / BK;

  __shared__ __align__(16) bf16 As[2][2][128 * 64];
  __shared__ __align__(16) bf16 Bs[2][2][(BN / 2) * 64];

  const int tid = threadIdx.x;
  const int lane = tid & 63, wave = tid >> 6;
  const int lo = lane & 15, hi = lane >> 4, lo7 = lane & 7;
  const int wm = wave >> 2, wn = wave & 3;
  const int m0 = blockIdx.x * BM, n0 = blockIdx.y * BN;

  const bf16* Ag = A  + (size_t)m0 * Kd;
  const bf16* Bg = Bt + (size_t)n0 * Kd;

  // A half h = row bands {h*64..h*64+63} and {128+h*64..}: quadrant mh of both
  // wave-M groups. Chunks linear in LDS; source col pre-swizzled by row&7.
  auto SA = [&](int h, int b, int kt) {
    #pragma unroll
    for (int l = 0; l < 2; l++) {
      const int ch = l * 512 + tid;
      const int r = (ch >> 3) & 63;
      const int row = ((ch >> 9) << 7) + h * 64 + r;
      const int slot = (ch & 7) ^ (r & 7);
      gll16(Ag + (size_t)row * Kd + kt * BK + slot * 8, &As[b][h][0] + ch * 8);
    }
  };
  // B half h = per-wave-group bands of BN/8 rows.
  auto SB = [&](int h, int b, int kt) {
    #pragma unroll
    for (int l = 0; l < BLOADS; l++) {
      const int ch = l * 512 + tid;
      int row, r;
      if constexpr (BN == 256) { r = (ch >> 3) & 31; row = ((ch >> 8) << 6) + h * 32 + r; }
      else                     { r = (ch >> 3) & 15; row = ((ch >> 7) << 5) + h * 16 + r; }
      const int slot = (ch & 7) ^ (r & 7);
      gll16(Bg + (size_t)row * Kd + kt * BK + slot * 8, &Bs[b][h][0] + ch * 8);
    }
  };

  auto RA = [&](int h, int b, short8 (&af)[MRh][2]) {
    #pragma unroll
    for (int i = 0; i < MRh; i++)
      #pragma unroll
      for (int kk = 0; kk < 2; kk++)
        af[i][kk] = *(const short8*)&As[b][h][(wm * 64 + i * 16 + lo) * 64 +
                                             (((kk * 4 + hi) ^ lo7) * 8)];
  };
  auto RB = [&](int h, int b, short8 (&bf)[NRh][2]) {
    #pragma unroll
    for (int j = 0; j < NRh; j++)
      #pragma unroll
      for (int kk = 0; kk < 2; kk++)
        bf[j][kk] = *(const short8*)&Bs[b][h][(wn * (BN / 8) + j * 16 + lo) * 64 +
                                              (((kk * 4 + hi) ^ lo7) * 8)];
  };

  floatx4 acc[MR][NR];
  #pragma unroll
  for (int i = 0; i < MR; i++)
    #pragma unroll
    for (int j = 0; j < NR; j++)
      #pragma unroll
      for (int r = 0; r < 4; r++) acc[i][j][r] = 0.0f;

  short8 af[MRh][2], bf0[NRh][2], bf1[NRh][2];

  auto MM = [&](int mh, int nh, short8 (&a)[MRh][2], short8 (&bb)[NRh][2]) {
    __builtin_amdgcn_s_setprio(1);
    #pragma unroll
    for (int kk = 0; kk < 2; kk++)
      #pragma unroll
      for (int i = 0; i < MRh; i++)
        #pragma unroll
        for (int j = 0; j < NRh; j++)
          acc[mh * MRh + i][nh * NRh + j] = __builtin_amdgcn_mfma_f32_16x16x32_bf16(
              a[i][kk], bb[j][kk], acc[mh * MRh + i][nh * NRh + j], 0, 0, 0);
    __builtin_amdgcn_s_setprio(0);
  };
  auto BAR = [&]() {
    __builtin_amdgcn_s_barrier();
    __builtin_amdgcn_sched_barrier(0);
  };

  // prologue: stage tile 0 fully
  SA(0, 0, 0); SB(0, 0, 0); SA(1, 0, 0); SB(1, 0, 0);

  for (int t = 0; t < NT; ++t) {
    const int b = t & 1, bn = b ^ 1;
    const bool L = (t + 1 == NT);
    // ---- phase 0: quadrant (m0,n0). Stage A0(t+1); wait for ALL of tile t.
    if (!L) { SA(0, bn, t + 1); asm volatile("s_waitcnt vmcnt(2)" ::: "memory"); }
    else    { asm volatile("s_waitcnt vmcnt(0)" ::: "memory"); }
    BAR();
    RA(0, b, af); RB(0, b, bf0);
    MM(0, 0, af, bf0);
    BAR();
    // ---- phase 1: (m0,n1). Reads pre-barrier (data guaranteed at phase 0).
    RB(1, b, bf1);
    if (!L) SB(0, bn, t + 1);
    BAR();
    MM(0, 1, af, bf1);
    BAR();
    // ---- phase 2: (m1,n1)
    RA(1, b, af);
    if (!L) SA(1, bn, t + 1);
    BAR();
    MM(1, 1, af, bf1);
    BAR();
    // ---- phase 3: (m1,n0)
    if (!L) SB(1, bn, t + 1);
    BAR();
    MM(1, 0, af, bf0);
    BAR();
  }

  #pragma unroll
  for (int ri = 0; ri < MR; ri++) {
    const int mb = m0 + wm * 128 + (ri >> 2) * 64 + (ri & 3) * 16 + hi * 4;
    #pragma unroll
    for (int cj = 0; cj < NR; cj++) {
      const int n = n0 + wn * (BN / 4) + (cj / NRh) * (BN / 8) + (cj % NRh) * 16 + lo;
      if constexpr (MODE == 6) {
        const int z = n >> 10, nz = n & 1023;
        const int bx = mb >> 11, hhh = nz >> 6, d = nz & 63;
        bf16* ob = (bf16*)outp + ((size_t)z << 23);
        if (z == 2) {
          ushort4 pk;
          pk.x = f2bu(acc[ri][cj][0]); pk.y = f2bu(acc[ri][cj][1]);
          pk.z = f2bu(acc[ri][cj][2]); pk.w = f2bu(acc[ri][cj][3]);
          *(ushort4*)&ob[((size_t)(bx * HEADS + hhh) * HDIM + d) * SEQ + (mb & 2047)] = pk;
        } else {
          const float sc = (z == 0) ? 0.125f : 1.0f;
          #pragma unroll
          for (int r = 0; r < 4; r++) {
            const int ss = (mb + r) & 2047;
            ob[((size_t)(bx * HEADS + hhh) * SEQ + ss) * HDIM + d] =
                __float2bfloat16(acc[ri][cj][r] * sc);
          }
        }
      } else if constexpr (MODE == 3) {
        #pragma unroll
        for (int r = 0; r < 4; r++) {
          const int m = mb + r;
          ((float*)outp)[(size_t)m * EMB + n] =
              acc[ri][cj][r] + bias[n] + resid[(size_t)m * EMB + n];
        }
      } else if constexpr (MODE == 4) {
        #pragma unroll
        for (int r = 0; r < 4; r++)
          ((bf16*)outp)[(size_t)(mb + r) * FFDIM + n] =
              __float2bfloat16(gelu_f(acc[ri][cj][r] + bias[n]));
      }
    }
  }
}

// ---- causal flash attention, staged + double-buffered (round-2 + T5) ----
__global__ __launch_bounds__(256, 2) void attn_kernel(
    const bf16* __restrict__ q, const bf16* __restrict__ k,
    const bf16* __restrict__ vt, bf16* __restrict__ ctx) {
  __shared__ __align__(16) char KVs[2][2][64 * 128];
  __shared__ __align__(16) char Pls[4][4096];
  const int bh = blockIdx.x, qt = blockIdx.y;
  const int tid = threadIdx.x;
  const int wave = tid >> 6, lane = tid & 63;
  const int lo = lane & 15, hi = lane >> 4;
  const int lo7 = lo & 7;
  const int q0 = qt * 128;
  const int q0w = q0 + wave * 32;
  const int qmax = q0w + 31;

  const bf16* qp = q  + ((size_t)bh * SEQ + q0w) * HDIM;
  const bf16* kp = k  + (size_t)bh * SEQ * HDIM;
  const bf16* vp = vt + (size_t)bh * HDIM * SEQ;

  short8 qf[2][2];
  #pragma unroll
  for (int m = 0; m < 2; m++)
    #pragma unroll
    for (int kk = 0; kk < 2; kk++)
      qf[m][kk] = *(const short8*)&qp[(size_t)(m * 16 + lo) * HDIM + kk * 32 + hi * 8];

  float m_run[2] = {-1e30f, -1e30f};
  float l_run[2] = {0.0f, 0.0f};
  floatx4 o[4][2];
  #pragma unroll
  for (int df = 0; df < 4; df++)
    #pragma unroll
    for (int m = 0; m < 2; m++)
      #pragma unroll
      for (int r = 0; r < 4; r++) o[df][m][r] = 0.0f;

  const int nt = 2 * qt + 2;

  const int c0 = tid, c1 = tid + 256;
  const int r0 = c0 >> 3, s0 = (c0 & 7) ^ (r0 & 7);
  const int r1 = c1 >> 3, s1 = (c1 & 7) ^ (r1 & 7);

  gll16(kp + (size_t)r0 * HDIM + s0 * 8, (bf16*)&KVs[0][0][c0 * 16]);
  gll16(vp + (size_t)r0 * SEQ + s0 * 8,  (bf16*)&KVs[0][1][c0 * 16]);
  gll16(kp + (size_t)r1 * HDIM + s1 * 8, (bf16*)&KVs[0][0][c1 * 16]);
  gll16(vp + (size_t)r1 * SEQ + s1 * 8,  (bf16*)&KVs[0][1][c1 * 16]);

  for (int t = 0; t < nt; ++t) {
    const int buf = t & 1;
    const int k0 = t * KVB;
    if (t + 1 < nt) {
      const int kn = k0 + KVB;
      gll16(kp + (size_t)(kn + r0) * HDIM + s0 * 8, (bf16*)&KVs[buf ^ 1][0][c0 * 16]);
      gll16(vp + (size_t)r0 * SEQ + kn + s0 * 8,    (bf16*)&KVs[buf ^ 1][1][c0 * 16]);
      gll16(kp + (size_t)(kn + r1) * HDIM + s1 * 8, (bf16*)&KVs[buf ^ 1][0][c1 * 16]);
      gll16(vp + (size_t)r1 * SEQ + kn + s1 * 8,    (bf16*)&KVs[buf ^ 1][1][c1 * 16]);
      asm volatile("s_waitcnt vmcnt(4)" ::: "memory");
    } else {
      asm volatile("s_waitcnt vmcnt(0)" ::: "memory");
    }
    __builtin_amdgcn_s_barrier();
    __builtin_amdgcn_sched_barrier(0);

    if (k0 <= qmax) {
      const char* Kb = KVs[buf][0];
      const char* Vb = KVs[buf][1];
      floatx4 sfr[4][2];
      __builtin_amdgcn_s_setprio(1);
      #pragma unroll
      for (int kf = 0; kf < 4; kf++) {
        const int rowb = (kf * 16 + lo) * 128;
        short8 kf0 = *(const short8*)(Kb + rowb + (( 0 + hi * 16) ^ (lo7 << 4)));
        short8 kf1 = *(const short8*)(Kb + rowb + ((64 + hi * 16) ^ (lo7 << 4)));
        #pragma unroll
        for (int m = 0; m < 2; m++) {
          floatx4 z = {0.0f, 0.0f, 0.0f, 0.0f};
          z = __builtin_amdgcn_mfma_f32_16x16x32_bf16(kf0, qf[m][0], z, 0, 0, 0);
          z = __builtin_amdgcn_mfma_f32_16x16x32_bf16(kf1, qf[m][1], z, 0, 0, 0);
          sfr[kf][m] = z;
        }
      }
      __builtin_amdgcn_s_setprio(0);
      if (k0 + KVB - 1 > q0w) {
        #pragma unroll
        for (int m = 0; m < 2; m++) {
          const int qg = q0w + m * 16 + lo;
          #pragma unroll
          for (int kf = 0; kf < 4; kf++)
            #pragma unroll
            for (int r = 0; r < 4; r++) {
              const int key = k0 + kf * 16 + hi * 4 + r;
              if (key > qg) sfr[kf][m][r] = -1e30f;
            }
        }
      }
      float alpha[2];
      #pragma unroll
      for (int m = 0; m < 2; m++) {
        float tmax = -1e30f;
        #pragma unroll
        for (int kf = 0; kf < 4; kf++)
          #pragma unroll
          for (int r = 0; r < 4; r++) tmax = fmaxf(tmax, sfr[kf][m][r]);
        tmax = fmaxf(tmax, __shfl_xor(tmax, 16));
        tmax = fmaxf(tmax, __shfl_xor(tmax, 32));
        const float mn = fmaxf(m_run[m], tmax);
        alpha[m] = __expf(m_run[m] - mn);
        m_run[m] = mn;
        float ps = 0.0f;
        const int prow = (m * 16 + lo) * 128;
        #pragma unroll
        for (int kf = 0; kf < 4; kf++) {
          float p0 = __expf(sfr[kf][m][0] - mn);
          float p1 = __expf(sfr[kf][m][1] - mn);
          float p2 = __expf(sfr[kf][m][2] - mn);
          float p3 = __expf(sfr[kf][m][3] - mn);
          ps += (p0 + p1) + (p2 + p3);
          ushort4 pk;
          pk.x = f2bu(p0); pk.y = f2bu(p1); pk.z = f2bu(p2); pk.w = f2bu(p3);
          *(ushort4*)(Pls[wave] + prow + ((kf * 32 + hi * 8) ^ (lo7 << 4))) = pk;
        }
        ps += __shfl_xor(ps, 16);
        ps += __shfl_xor(ps, 32);
        l_run[m] = l_run[m] * alpha[m] + ps;
      }
      asm volatile("s_waitcnt lgkmcnt(0)" ::: "memory");
      __builtin_amdgcn_sched_barrier(0);
      short8 pa[2][2];
      #pragma unroll
      for (int m = 0; m < 2; m++)
        #pragma unroll
        for (int kk2 = 0; kk2 < 2; kk2++)
          pa[m][kk2] = *(const short8*)(Pls[wave] + (m * 16 + lo) * 128 +
                                        ((kk2 * 64 + hi * 16) ^ (lo7 << 4)));
      float ar[2][4];
      #pragma unroll
      for (int m = 0; m < 2; m++)
        #pragma unroll
        for (int r = 0; r < 4; r++) ar[m][r] = __shfl(alpha[m], hi * 4 + r);
      #pragma unroll
      for (int df = 0; df < 4; df++)
        #pragma unroll
        for (int m = 0; m < 2; m++)
          #pragma unroll
          for (int r = 0; r < 4; r++) o[df][m][r] *= ar[m][r];
      __builtin_amdgcn_s_setprio(1);
      #pragma unroll
      for (int df = 0; df < 4; df++) {
        const int rowb = (df * 16 + lo) * 128;
        short8 vf0 = *(const short8*)(Vb + rowb + (( 0 + hi * 16) ^ (lo7 << 4)));
        short8 vf1 = *(const short8*)(Vb + rowb + ((64 + hi * 16) ^ (lo7 << 4)));
        #pragma unroll
        for (int m = 0; m < 2; m++) {
          o[df][m] = __builtin_amdgcn_mfma_f32_16x16x32_bf16(pa[m][0], vf0, o[df][m], 0, 0, 0);
          o[df][m] = __builtin_amdgcn_mfma_f32_16x16x32_bf16(pa[m][1], vf1, o[df][m], 0, 0, 0);
        }
      }
      __builtin_amdgcn_s_setprio(0);
    }
    __builtin_amdgcn_s_barrier();
    __builtin_amdgcn_sched_barrier(0);
  }

  const int b = bh >> 4, hh = bh & 15;
  #pragma unroll
  for (int m = 0; m < 2; m++) {
    float lr[4];
    #pragma unroll
    for (int r = 0; r < 4; r++) lr[r] = __shfl(l_run[m], hi * 4 + r);
    #pragma unroll
    for (int df = 0; df < 4; df++)
      #pragma unroll
      for (int r = 0; r < 4; r++) {
        const int srow = q0w + m * 16 + hi * 4 + r;
        ctx[((size_t)(b * SEQ + srow)) * EMB + hh * HDIM + df * 16 + lo] =
            __float2bfloat16(o[df][m][r] / lr[r]);
      }
  }
}

extern "C" void kernel_launch(void* const* d_in, const int* in_sizes, int n_in,
                              void* d_out, int out_size, void* d_ws, size_t ws_size,
                              hipStream_t stream) {
  const float* x   = (const float*)d_in[0];
  const float* Wq  = (const float*)d_in[1];
  const float* Wk  = (const float*)d_in[2];
  const float* Wv  = (const float*)d_in[3];
  const float* Wo  = (const float*)d_in[4];
  const float* bo  = (const float*)d_in[5];
  const float* l1s = (const float*)d_in[6];
  const float* l1b = (const float*)d_in[7];
  const float* l2s = (const float*)d_in[8];
  const float* l2b = (const float*)d_in[9];
  const float* W1  = (const float*)d_in[10];
  const float* b1  = (const float*)d_in[11];
  const float* W2  = (const float*)d_in[12];
  const float* b2  = (const float*)d_in[13];
  float* out = (float*)d_out;

  char* ws = (char*)d_ws;
  bf16* hbuf   = (bf16*)(ws);
  bf16* qbuf   = (bf16*)(ws + ((size_t)16 << 20));
  bf16* kbuf   = (bf16*)(ws + ((size_t)32 << 20));
  bf16* vbuf   = (bf16*)(ws + ((size_t)48 << 20));
  bf16* ctxbuf = hbuf;
  bf16* gbuf   = (bf16*)(ws);
  bf16* h2buf  = (bf16*)(ws + ((size_t)64 << 20));
  bf16* WqT    = (bf16*)(ws + ((size_t)80 << 20));
  bf16* WkT    = WqT + (1u << 20);
  bf16* WvT    = WkT + (1u << 20);
  bf16* WoT    = WvT + (1u << 20);
  bf16* W1T    = WoT + (1u << 20);
  bf16* W2T    = W1T + (4u << 20);

  wconv_kernel<<<dim3(32, 32), 256, 0, stream>>>(Wq, WqT, 1024, 1024);
  wconv_kernel<<<dim3(32, 32), 256, 0, stream>>>(Wk, WkT, 1024, 1024);
  wconv_kernel<<<dim3(32, 32), 256, 0, stream>>>(Wv, WvT, 1024, 1024);
  wconv_kernel<<<dim3(32, 32), 256, 0, stream>>>(Wo, WoT, 1024, 1024);
  wconv_kernel<<<dim3(128, 32), 256, 0, stream>>>(W1, W1T, 1024, 4096);
  wconv_kernel<<<dim3(32, 128), 256, 0, stream>>>(W2, W2T, 4096, 1024);

  ln_kernel<<<8192, 256, 0, stream>>>(x, l1s, l1b, hbuf);

  // fused QKV: Bt = [WqT;WkT;WvT] (3072 x 1024 contiguous), 256x256 tile
  gemm8_kernel<256, 1024, 6><<<dim3(32, 12), 512, 0, stream>>>(
      hbuf, WqT, nullptr, nullptr, qbuf);

  attn_kernel<<<dim3(64, 16), 256, 0, stream>>>(qbuf, kbuf, vbuf, ctxbuf);

  // Wo + bias + residual (fp32 out), 256x128 tile
  gemm8_kernel<128, 1024, 3><<<dim3(32, 8), 512, 0, stream>>>(
      ctxbuf, WoT, bo, x, (void*)out);
  ln_kernel<<<8192, 256, 0, stream>>>(out, l2s, l2b, h2buf);
  // FF1: 256x256 tile, gelu
  gemm8_kernel<256, 1024, 4><<<dim3(32, 16), 512, 0, stream>>>(
      h2buf, W1T, b1, nullptr, gbuf);
  // FF2: 256x128 tile, K=4096, bias + residual (fp32 out)
  gemm8_kernel<128, 4096, 3><<<dim3(32, 8), 512, 0, stream>>>(
      gbuf, W2T, b2, out, (void*)out);
}